// Round 3
// baseline (882.662 us; speedup 1.0000x reference)
//
#include <hip/hip_runtime.h>
#include <hip/hip_bf16.h>

#define N_NODES 50000
#define N_EDGES 800000
#define N_RELS 65
#define DIM 64
#define N_GRAPHS 512
#define EPW 200  // edges per wave in msg kernel; 800000/200 = 4000 waves

#define SORT_BLOCKS 256
#define CHUNK ((N_EDGES + SORT_BLOCKS - 1) / SORT_BLOCKS)  // 3125

#define SCAN_BLK 512
#define NSCAN_BLKS ((N_NODES + SCAN_BLK - 1) / SCAN_BLK)   // 98

// ================= prep: rel-sort (block-stable counting sort) =================

__global__ __launch_bounds__(256) void hist2_kernel(const int* __restrict__ et,
                                                    int* __restrict__ blk_hist) {
    __shared__ int lh[N_RELS];
    int t = threadIdx.x, b = blockIdx.x;
    if (t < N_RELS) lh[t] = 0;
    __syncthreads();
    int lo = b * CHUNK;
    int hi = lo + CHUNK; if (hi > N_EDGES) hi = N_EDGES;
    for (int i = lo + t; i < hi; i += 256) atomicAdd(&lh[et[i]], 1);
    __syncthreads();
    if (t < N_RELS) blk_hist[b * N_RELS + t] = lh[t];
}

// column scan over blocks + relation bases; also emits rel_ptr[66]
__global__ __launch_bounds__(128) void relscan_kernel(const int* __restrict__ blk_hist,
                                                      int* __restrict__ blk_off,
                                                      int* __restrict__ rel_ptr) {
    __shared__ int total[N_RELS];
    __shared__ int rel_base[N_RELS];
    int r = threadIdx.x;
    if (r < N_RELS) {
        int run = 0;
        for (int b = 0; b < SORT_BLOCKS; ++b) {
            int idx = b * N_RELS + r;
            int v = blk_hist[idx];
            blk_off[idx] = run;
            run += v;
        }
        total[r] = run;
    }
    __syncthreads();
    if (r == 0) {
        int s = 0;
        for (int q = 0; q < N_RELS; ++q) { rel_base[q] = s; s += total[q]; }
        rel_ptr[N_RELS] = N_EDGES;
    }
    __syncthreads();
    if (r < N_RELS) {
        int base = rel_base[r];
        rel_ptr[r] = base;
        for (int b = 0; b < SORT_BLOCKS; ++b) blk_off[b * N_RELS + r] += base;
    }
}

__global__ __launch_bounds__(256) void scatter2_kernel(
    const int* __restrict__ et, const int* __restrict__ src,
    const int* __restrict__ dst, const int* __restrict__ blk_off,
    int* __restrict__ src_s, int* __restrict__ dst_s) {
    __shared__ int cur[N_RELS];
    int t = threadIdx.x, b = blockIdx.x;
    if (t < N_RELS) cur[t] = blk_off[b * N_RELS + t];
    __syncthreads();
    int lo = b * CHUNK;
    int hi = lo + CHUNK; if (hi > N_EDGES) hi = N_EDGES;
    for (int i = lo + t; i < hi; i += 256) {
        int r = et[i];
        int p = atomicAdd(&cur[r], 1);
        src_s[p] = src[i];
        dst_s[p] = dst[i];
    }
}

// ================= prep: dst CSR =================

__global__ void histdst_kernel(const int* __restrict__ dst, int* __restrict__ cnt_d) {
    int i = blockIdx.x * 256 + threadIdx.x;
    if (i < N_EDGES) atomicAdd(&cnt_d[dst[i]], 1);
}

// two-level exclusive scan over 50000
__global__ __launch_bounds__(SCAN_BLK) void scanblk_kernel(const int* __restrict__ cnt,
                                                           int* __restrict__ outv,
                                                           int* __restrict__ blk_tot) {
    __shared__ int tmp[SCAN_BLK];
    int t = threadIdx.x;
    int i = blockIdx.x * SCAN_BLK + t;
    int v = (i < N_NODES) ? cnt[i] : 0;
    tmp[t] = v;
    __syncthreads();
    for (int off = 1; off < SCAN_BLK; off <<= 1) {
        int add = (t >= off) ? tmp[t - off] : 0;
        __syncthreads();
        tmp[t] += add;
        __syncthreads();
    }
    if (i < N_NODES) outv[i] = tmp[t] - v;  // exclusive
    if (t == SCAN_BLK - 1) blk_tot[blockIdx.x] = tmp[t];
}

__global__ void scantop_kernel(int* __restrict__ blk_tot, int* __restrict__ blk_base) {
    if (threadIdx.x == 0 && blockIdx.x == 0) {
        int run = 0;
        for (int b = 0; b < NSCAN_BLKS; ++b) { blk_base[b] = run; run += blk_tot[b]; }
    }
}

__global__ __launch_bounds__(SCAN_BLK) void scanadd_kernel(int* __restrict__ outv,
                                                           const int* __restrict__ blk_base) {
    int i = blockIdx.x * SCAN_BLK + threadIdx.x;
    if (i < N_NODES) outv[i] += blk_base[blockIdx.x];
}

// rank each rel-sorted edge within its dst bin -> dst-sorted slot
__global__ void dpos_kernel(const int* __restrict__ dst_s, int* __restrict__ cursor,
                            int* __restrict__ dpos) {
    int i = blockIdx.x * 256 + threadIdx.x;
    if (i < N_EDGES) dpos[i] = atomicAdd(&cursor[dst_s[i]], 1);
}

// ================= prep: graph segments (graph_ids sorted) =================

__global__ void histgid_kernel(const int* __restrict__ gid, int* __restrict__ cnt_g) {
    int i = blockIdx.x * 256 + threadIdx.x;
    if (i < N_NODES) atomicAdd(&cnt_g[gid[i]], 1);
}

__global__ __launch_bounds__(512) void scangid_kernel(const int* __restrict__ cnt_g,
                                                      int* __restrict__ g_ptr) {
    __shared__ int tmp[512];
    int t = threadIdx.x;
    int v = (t < N_GRAPHS) ? cnt_g[t] : 0;
    tmp[t] = v;
    __syncthreads();
    for (int off = 1; off < 512; off <<= 1) {
        int add = (t >= off) ? tmp[t - off] : 0;
        __syncthreads();
        tmp[t] += add;
        __syncthreads();
    }
    if (t < N_GRAPHS) g_ptr[t] = tmp[t] - v;
}

// ================= phase 1: per-edge message (rel-sorted, register W) =================
// One wave per EPW rel-sorted edges. Outer loop over relation segments: wcol
// loaded UNCONDITIONALLY at segment top -> compiler promotes to VGPRs.
// src wave-uniform -> h-row via scalar loads. 4 accumulators break the FMA chain.
// Plain bf16 store to the edge's dst-sorted slot (no atomics).

__global__ __launch_bounds__(256) void msg_kernel(
    const float* __restrict__ h, const float* __restrict__ W,
    const int* __restrict__ rel_ptr, const int* __restrict__ src_s,
    const int* __restrict__ dpos, __hip_bfloat16* __restrict__ msg) {
    int wave = blockIdx.x * 4 + (threadIdx.x >> 6);
    int lane = threadIdx.x & 63;
    int e0 = wave * EPW;
    if (e0 >= N_EDGES) return;
    int e1 = e0 + EPW;
    if (e1 > N_EDGES) e1 = N_EDGES;

    // binary search: r with rel_ptr[r] <= e0 < rel_ptr[r+1]
    int lo = 0, hi = N_RELS;
    while (lo + 1 < hi) {
        int mid = (lo + hi) >> 1;
        if (rel_ptr[mid] <= e0) lo = mid; else hi = mid;
    }
    int r = lo;
    int e = e0;
    while (e < e1) {
        int seg_end = rel_ptr[r + 1];
        if (seg_end > e1) seg_end = e1;
        if (seg_end > e) {
            const float* __restrict__ Wr = W + (size_t)r * (DIM * DIM);
            float wcol[DIM];
            #pragma unroll
            for (int d = 0; d < DIM; ++d) wcol[d] = Wr[d * DIM + lane];
            for (; e < seg_end; ++e) {
                int s = __builtin_amdgcn_readfirstlane(src_s[e]);
                int p = __builtin_amdgcn_readfirstlane(dpos[e]);
                const float* __restrict__ hrow = h + (size_t)s * DIM;
                float a0 = 0.f, a1 = 0.f, a2 = 0.f, a3 = 0.f;
                #pragma unroll
                for (int d = 0; d < DIM; d += 4) {
                    a0 += hrow[d + 0] * wcol[d + 0];
                    a1 += hrow[d + 1] * wcol[d + 1];
                    a2 += hrow[d + 2] * wcol[d + 2];
                    a3 += hrow[d + 3] * wcol[d + 3];
                }
                msg[(size_t)p * DIM + lane] = __float2bfloat16((a0 + a1) + (a2 + a3));
            }
        }
        ++r;
    }
}

// ================= phase 2: pull-aggregate + bias + ReLU =================
// One wave per node; msg rows for a node are contiguous (dst-sorted slots).

__global__ __launch_bounds__(256) void agg_kernel(
    const __hip_bfloat16* __restrict__ msg, const int* __restrict__ row_ptr,
    const int* __restrict__ cnt_d, const float* __restrict__ b,
    float* __restrict__ hout) {
    int wave = blockIdx.x * 4 + (threadIdx.x >> 6);
    int lane = threadIdx.x & 63;
    if (wave >= N_NODES) return;
    int j0 = row_ptr[wave];
    int n  = cnt_d[wave];
    float a0 = 0.f, a1 = 0.f;
    int j = 0;
    for (; j + 1 < n; j += 2) {
        a0 += __bfloat162float(msg[(size_t)(j0 + j) * DIM + lane]);
        a1 += __bfloat162float(msg[(size_t)(j0 + j + 1) * DIM + lane]);
    }
    if (j < n) a0 += __bfloat162float(msg[(size_t)(j0 + j) * DIM + lane]);
    float v = a0 + a1 + b[lane];
    hout[(size_t)wave * DIM + lane] = v > 0.f ? v : 0.f;
}

// ================= graph sum-pool (segmented, no atomics) =================

__global__ __launch_bounds__(256) void pool_seg_kernel(
    const float* __restrict__ h, const int* __restrict__ g_ptr,
    const int* __restrict__ cnt_g, float* __restrict__ g) {
    int wave = blockIdx.x * 4 + (threadIdx.x >> 6);
    int lane = threadIdx.x & 63;
    if (wave >= N_GRAPHS) return;
    int j0 = g_ptr[wave];
    int n  = cnt_g[wave];
    float a0 = 0.f, a1 = 0.f;
    int j = 0;
    for (; j + 1 < n; j += 2) {
        a0 += h[(size_t)(j0 + j) * DIM + lane];
        a1 += h[(size_t)(j0 + j + 1) * DIM + lane];
    }
    if (j < n) a0 += h[(size_t)(j0 + j) * DIM + lane];
    g[(size_t)wave * DIM + lane] = a0 + a1;
}

// ================= fused FC x3 + prediction head =================

__global__ __launch_bounds__(256) void fc_kernel(
    const float* __restrict__ g,
    const float* __restrict__ W1, const float* __restrict__ b1,
    const float* __restrict__ W2, const float* __restrict__ b2,
    const float* __restrict__ W3, const float* __restrict__ b3,
    const float* __restrict__ pW, const float* __restrict__ pb,
    float* __restrict__ out) {
    int wave = blockIdx.x * 4 + (threadIdx.x >> 6);
    int lane = threadIdx.x & 63;
    if (wave >= N_GRAPHS) return;

    float v = g[(size_t)wave * DIM + lane];

    const float* Ws[3] = {W1, W2, W3};
    const float* bs[3] = {b1, b2, b3};
    for (int l = 0; l < 3; ++l) {
        float acc = bs[l][lane];
        const float* __restrict__ Wl = Ws[l];
        #pragma unroll
        for (int d = 0; d < DIM; ++d)
            acc += __shfl(v, d) * Wl[d * DIM + lane];
        v = acc > 0.f ? acc : 0.f;
    }

    float p0 = v * pW[lane * 2 + 0];
    float p1 = v * pW[lane * 2 + 1];
    #pragma unroll
    for (int off = 32; off > 0; off >>= 1) {
        p0 += __shfl_down(p0, off);
        p1 += __shfl_down(p1, off);
    }
    if (lane == 0) {
        out[wave * 2 + 0] = p0 + pb[0];
        out[wave * 2 + 1] = p1 + pb[1];
    }
}

// ================= launch =================

extern "C" void kernel_launch(void* const* d_in, const int* in_sizes, int n_in,
                              void* d_out, int out_size, void* d_ws, size_t ws_size,
                              hipStream_t stream) {
    const float* node_feats = (const float*)d_in[0];
    const int*   etypes     = (const int*)d_in[1];
    const int*   src        = (const int*)d_in[2];
    const int*   dst        = (const int*)d_in[3];
    const int*   graph_ids  = (const int*)d_in[4];
    const float* W1 = (const float*)d_in[5];
    const float* b1 = (const float*)d_in[6];
    const float* W2 = (const float*)d_in[7];
    const float* b2 = (const float*)d_in[8];
    const float* W3 = (const float*)d_in[9];
    const float* b3 = (const float*)d_in[10];
    const float* fcW1 = (const float*)d_in[11];
    const float* fcb1 = (const float*)d_in[12];
    const float* fcW2 = (const float*)d_in[13];
    const float* fcb2 = (const float*)d_in[14];
    const float* fcW3 = (const float*)d_in[15];
    const float* fcb3 = (const float*)d_in[16];
    const float* pW = (const float*)d_in[17];
    const float* pb = (const float*)d_in[18];
    float* out = (float*)d_out;

    // workspace carve-up (256B aligned)
    char* p = (char*)d_ws;
    auto alloc = [&](size_t bytes) -> void* {
        void* r = (void*)p;
        p += (bytes + 255) & ~(size_t)255;
        return r;
    };
    int* blk_hist = (int*)alloc((size_t)SORT_BLOCKS * N_RELS * sizeof(int));
    int* blk_off  = (int*)alloc((size_t)SORT_BLOCKS * N_RELS * sizeof(int));
    int* rel_ptr  = (int*)alloc((N_RELS + 1) * sizeof(int));
    int* src_s    = (int*)alloc((size_t)N_EDGES * sizeof(int));
    int* dst_s    = (int*)alloc((size_t)N_EDGES * sizeof(int));
    int* dpos     = (int*)alloc((size_t)N_EDGES * sizeof(int));
    int* cnt_d    = (int*)alloc((size_t)N_NODES * sizeof(int));
    int* row_ptr  = (int*)alloc((size_t)N_NODES * sizeof(int));
    int* cursor_d = (int*)alloc((size_t)N_NODES * sizeof(int));
    int* blk_tot  = (int*)alloc(NSCAN_BLKS * sizeof(int));
    int* blk_base = (int*)alloc(NSCAN_BLKS * sizeof(int));
    int* cnt_g    = (int*)alloc(N_GRAPHS * sizeof(int));
    int* g_ptr    = (int*)alloc(N_GRAPHS * sizeof(int));
    float* hA     = (float*)alloc((size_t)N_NODES * DIM * sizeof(float));
    float* hB     = (float*)alloc((size_t)N_NODES * DIM * sizeof(float));
    float* g      = (float*)alloc((size_t)N_GRAPHS * DIM * sizeof(float));
    __hip_bfloat16* msg = (__hip_bfloat16*)alloc((size_t)N_EDGES * DIM * sizeof(__hip_bfloat16));

    const int EBLK = (N_EDGES + 255) / 256;              // 3125
    const int NBLK256 = (N_NODES + 255) / 256;           // 196
    const int MSG_BLOCKS = (N_EDGES / EPW + 3) / 4;      // 1000
    const int AGG_BLOCKS = (N_NODES + 3) / 4;            // 12500

    // ---- prep: rel-sort ----
    hist2_kernel<<<SORT_BLOCKS, 256, 0, stream>>>(etypes, blk_hist);
    relscan_kernel<<<1, 128, 0, stream>>>(blk_hist, blk_off, rel_ptr);
    scatter2_kernel<<<SORT_BLOCKS, 256, 0, stream>>>(etypes, src, dst, blk_off,
                                                     src_s, dst_s);

    // ---- prep: dst CSR ----
    hipMemsetAsync(cnt_d, 0, (size_t)N_NODES * sizeof(int), stream);
    histdst_kernel<<<EBLK, 256, 0, stream>>>(dst, cnt_d);
    scanblk_kernel<<<NSCAN_BLKS, SCAN_BLK, 0, stream>>>(cnt_d, row_ptr, blk_tot);
    scantop_kernel<<<1, 64, 0, stream>>>(blk_tot, blk_base);
    scanadd_kernel<<<NSCAN_BLKS, SCAN_BLK, 0, stream>>>(row_ptr, blk_base);
    hipMemcpyAsync(cursor_d, row_ptr, (size_t)N_NODES * sizeof(int),
                   hipMemcpyDeviceToDevice, stream);
    dpos_kernel<<<EBLK, 256, 0, stream>>>(dst_s, cursor_d, dpos);

    // ---- prep: graph segments ----
    hipMemsetAsync(cnt_g, 0, N_GRAPHS * sizeof(int), stream);
    histgid_kernel<<<NBLK256, 256, 0, stream>>>(graph_ids, cnt_g);
    scangid_kernel<<<1, 512, 0, stream>>>(cnt_g, g_ptr);

    // ---- 3 RGCN layers ----
    msg_kernel<<<MSG_BLOCKS, 256, 0, stream>>>(node_feats, W1, rel_ptr, src_s, dpos, msg);
    agg_kernel<<<AGG_BLOCKS, 256, 0, stream>>>(msg, row_ptr, cnt_d, b1, hA);

    msg_kernel<<<MSG_BLOCKS, 256, 0, stream>>>(hA, W2, rel_ptr, src_s, dpos, msg);
    agg_kernel<<<AGG_BLOCKS, 256, 0, stream>>>(msg, row_ptr, cnt_d, b2, hB);

    msg_kernel<<<MSG_BLOCKS, 256, 0, stream>>>(hB, W3, rel_ptr, src_s, dpos, msg);
    agg_kernel<<<AGG_BLOCKS, 256, 0, stream>>>(msg, row_ptr, cnt_d, b3, hA);

    // ---- pool + FC head ----
    pool_seg_kernel<<<(N_GRAPHS + 3) / 4, 256, 0, stream>>>(hA, g_ptr, cnt_g, g);
    fc_kernel<<<(N_GRAPHS + 3) / 4, 256, 0, stream>>>(g, fcW1, fcb1, fcW2, fcb2,
                                                      fcW3, fcb3, pW, pb, out);
}